// Round 4
// baseline (535.906 us; speedup 1.0000x reference)
//
#include <hip/hip_runtime.h>

// Fused 2-layer LSTM (B=4096, S=512, H=64) + dense(64->32 relu)->dense(32->24).
// R4: barrier-FREE step loop. 512-thr WG (8 waves) per 16-row tile, grid=256.
// Waves 0-3: layer-1; waves 4-7: layer-2 (delayed one step:
// z2[t-1] = b2 + Wih2@h1[t-1] + Whh2@h2[t-2]).
// h1/h2 are depth-4 LDS ring buffers (slot = step&3). Sync via LDS counters:
//   cnt1[t]==4  : h1[t] fully committed (acquire/release)
//   cnt2[t]==4  : h2[t] fully committed
//   done[t]==8  : all waves finished step t -> slot t%4 reusable at step t+4
// No __syncthreads in the loop => waves drift out of phase, so one wave's
// trans-heavy gate math hides another's ds_read/MFMA latency on the same SIMD.

typedef __attribute__((ext_vector_type(8))) short bf16x8;
typedef __attribute__((ext_vector_type(4))) float floatx4;

#define SEQ 512
#define HID 64
#define LOG2E 1.4426950408889634f

__device__ inline floatx4 MFMA(bf16x8 a, bf16x8 b, floatx4 c) {
    return __builtin_amdgcn_mfma_f32_16x16x32_bf16(a, b, c, 0, 0, 0);
}
__device__ inline short f2bf(float f) {
    __bf16 b = (__bf16)f;
    return __builtin_bit_cast(short, b);
}
__device__ inline float exp2_fast(float x) {
#if __has_builtin(__builtin_amdgcn_exp2f)
    return __builtin_amdgcn_exp2f(x);
#else
    return __expf(x * 0.6931471805599453f);
#endif
}
__device__ inline float rcp_fast(float x) { return __builtin_amdgcn_rcpf(x); }

// z* pre-scaled: zi=-i*log2e, zf=-f*log2e, zg=-2g*log2e, zo=-o*log2e.
__device__ inline float lstm_gate(float zi, float zf, float zg, float zo, float& c) {
    float ei = exp2_fast(zi);
    float ef = exp2_fast(zf);
    float eg = exp2_fast(zg);
    float eo = exp2_fast(zo);
    float P  = (1.0f + ei) * (1.0f + eg);
    float F  = 1.0f + ef;
    float num = c * P + (1.0f - eg) * F;
    c = num * rcp_fast(P * F);
    float ec = exp2_fast(fminf(c * (-2.0f * LOG2E), 40.0f));
    return (1.0f - ec) * rcp_fast((1.0f + eo) * (1.0f + ec));
}

__device__ inline void wg_wait(int* addr, int target) {
    int guard = 0;
    while (__hip_atomic_load(addr, __ATOMIC_ACQUIRE, __HIP_MEMORY_SCOPE_WORKGROUP) < target) {
        __builtin_amdgcn_s_sleep(1);
        if (++guard > (1 << 22)) break;   // never expected; guarantees termination
    }
}
__device__ inline void wg_signal(int* addr) {
    if ((threadIdx.x & 63) == 0)
        (void)__hip_atomic_fetch_add(addr, 1, __ATOMIC_RELEASE, __HIP_MEMORY_SCOPE_WORKGROUP);
}

__global__ __launch_bounds__(512, 2) void lstm_fused(
    const float* __restrict__ x,
    const float* __restrict__ Wih1, const float* __restrict__ Whh1,
    const float* __restrict__ bih1, const float* __restrict__ bhh1,
    const float* __restrict__ Wih2, const float* __restrict__ Whh2,
    const float* __restrict__ bih2, const float* __restrict__ bhh2,
    const float* __restrict__ Wd1,  const float* __restrict__ bd1,
    const float* __restrict__ Wd2,  const float* __restrict__ bd2,
    float* __restrict__ out)
{
    const int tid  = threadIdx.x;
    const int wave = tid >> 6;
    const int ct   = wave & 3;       // column-tile (h-cols [16ct,16ct+16))
    const int is2  = wave >> 2;      // 0: layer-1 wave, 1: layer-2 wave
    const int lane = tid & 63;
    const int l15  = lane & 15;
    const int quad = lane >> 4;
    const int b0   = blockIdx.x * 16;

    __shared__ __align__(16) float x_s[16][516];      // 33 KB
    __shared__ __align__(16) short h1_s[4][16][72];   // ring, slot = step&3
    __shared__ __align__(16) short h2_s[4][16][72];
    __shared__ float y1_s[16][32];
    __shared__ int cnt1[SEQ], cnt2[SEQ], done[SEQ];

    // ---- stage x tile (16 rows x 512 f32) ----
    {
        const int row = tid >> 5;
        const int c0  = (tid & 31) * 16;
        const float4* src = reinterpret_cast<const float4*>(x + (size_t)(b0 + row) * SEQ + c0);
        float4* dst = reinterpret_cast<float4*>(&x_s[row][c0]);
        #pragma unroll
        for (int j = 0; j < 4; ++j) dst[j] = src[j];
    }
    {   // zero all ring slots (covers h1[-1], h2[-1], h2[-2]) and counters
        int* p1 = (int*)&h1_s[0][0][0];
        int* p2 = (int*)&h2_s[0][0][0];
        for (int i = tid; i < 4 * 16 * 72 / 2; i += 512) { p1[i] = 0; p2[i] = 0; }
        for (int i = tid; i < SEQ; i += 512) { cnt1[i] = 0; cnt2[i] = 0; done[i] = 0; }
    }

    // ---- per-wave weight B-fragments (pre-scaled by -log2e; gate g: -2log2e) ----
    bf16x8 Wf[4][4];
    float wxc[4], bcs[4];
    #pragma unroll
    for (int g = 0; g < 4; ++g) {
        const float sc = (g == 2) ? (-2.0f * LOG2E) : (-LOG2E);
        const int col = g * 64 + ct * 16 + l15;
        if (!is2) {
            wxc[g] = Wih1[col] * sc;
            bcs[g] = (bih1[col] + bhh1[col]) * sc;
        } else {
            wxc[g] = 0.0f;
            bcs[g] = (bih2[col] + bhh2[col]) * sc;
        }
        #pragma unroll
        for (int kt = 0; kt < 2; ++kt) {
            const int koff = kt * 32 + quad * 8;
            union { short s[8]; bf16x8 v; } u0, u1;
            #pragma unroll
            for (int j = 0; j < 8; ++j) {
                if (!is2) {
                    u0.s[j] = f2bf(Whh1[col * HID + koff + j] * sc);
                    u1.s[j] = 0;
                } else {
                    u0.s[j] = f2bf(Wih2[col * HID + koff + j] * sc);
                    u1.s[j] = f2bf(Whh2[col * HID + koff + j] * sc);
                }
            }
            Wf[kt][g] = u0.v;
            Wf[2 + kt][g] = u1.v;
        }
    }

    const int hcol = ct * 16 + l15;
    float cst[4] = {0, 0, 0, 0};

    __syncthreads();   // x staged, rings zeroed, counters zeroed

    for (int t = 0; t < SEQ; ++t) {
        const int sr1 = (t + 3) & 3;          // slot of h1[t-1]
        if (!is2) {
            if (t > 0) wg_wait(&cnt1[t - 1], 4);
            const bf16x8 A1a = *reinterpret_cast<const bf16x8*>(&h1_s[sr1][l15][quad * 8]);
            const bf16x8 A1b = *reinterpret_cast<const bf16x8*>(&h1_s[sr1][l15][32 + quad * 8]);
            floatx4 z[4];
            #pragma unroll
            for (int g = 0; g < 4; ++g)
                #pragma unroll
                for (int r = 0; r < 4; ++r)
                    z[g][r] = x_s[quad * 4 + r][t] * wxc[g] + bcs[g];
            #pragma unroll
            for (int g = 0; g < 4; ++g) {
                z[g] = MFMA(A1a, Wf[0][g], z[g]);
                z[g] = MFMA(A1b, Wf[1][g], z[g]);
            }
            float hv[4];
            #pragma unroll
            for (int r = 0; r < 4; ++r)
                hv[r] = lstm_gate(z[0][r], z[1][r], z[2][r], z[3][r], cst[r]);
            if (t >= 3) wg_wait(&done[t - 3], 8);   // slot t%4 reusable
            #pragma unroll
            for (int r = 0; r < 4; ++r)
                h1_s[t & 3][quad * 4 + r][hcol] = f2bf(hv[r]);
            wg_signal(&cnt1[t]);
        } else {
            if (t > 0) wg_wait(&cnt1[t - 1], 4);
            if (t > 1) wg_wait(&cnt2[t - 2], 4);
            const int sr2 = (t + 2) & 3;      // slot of h2[t-2]
            const bf16x8 A1a = *reinterpret_cast<const bf16x8*>(&h1_s[sr1][l15][quad * 8]);
            const bf16x8 A1b = *reinterpret_cast<const bf16x8*>(&h1_s[sr1][l15][32 + quad * 8]);
            const bf16x8 A2a = *reinterpret_cast<const bf16x8*>(&h2_s[sr2][l15][quad * 8]);
            const bf16x8 A2b = *reinterpret_cast<const bf16x8*>(&h2_s[sr2][l15][32 + quad * 8]);
            floatx4 z[4];
            #pragma unroll
            for (int g = 0; g < 4; ++g)
                z[g] = floatx4{bcs[g], bcs[g], bcs[g], bcs[g]};
            #pragma unroll
            for (int g = 0; g < 4; ++g) {
                z[g] = MFMA(A1a, Wf[0][g], z[g]);   // Wih2 @ h1[t-1]
                z[g] = MFMA(A1b, Wf[1][g], z[g]);
                z[g] = MFMA(A2a, Wf[2][g], z[g]);   // Whh2 @ h2[t-2]
                z[g] = MFMA(A2b, Wf[3][g], z[g]);
            }
            const float m2 = (t == 0) ? 0.0f : 1.0f;
            float hv[4];
            #pragma unroll
            for (int r = 0; r < 4; ++r) {
                float cc = cst[r];
                hv[r] = lstm_gate(z[0][r], z[1][r], z[2][r], z[3][r], cc) * m2;
                cst[r] = cc * m2;
            }
            if (t >= 3) wg_wait(&done[t - 3], 8);
            if (t > 0) {                       // h2[t-1] -> slot (t-1)&3
                #pragma unroll
                for (int r = 0; r < 4; ++r)
                    h2_s[(t + 3) & 3][quad * 4 + r][hcol] = f2bf(hv[r]);
                wg_signal(&cnt2[t - 1]);
            }
        }
        wg_signal(&done[t]);
    }

    // ---- drain: layer 2 for t = SEQ-1 (layer-2 waves only) ----
    if (is2) {
        wg_wait(&cnt1[SEQ - 1], 4);
        wg_wait(&cnt2[SEQ - 2], 4);
        const bf16x8 A1a = *reinterpret_cast<const bf16x8*>(&h1_s[(SEQ - 1) & 3][l15][quad * 8]);
        const bf16x8 A1b = *reinterpret_cast<const bf16x8*>(&h1_s[(SEQ - 1) & 3][l15][32 + quad * 8]);
        const bf16x8 A2a = *reinterpret_cast<const bf16x8*>(&h2_s[(SEQ - 2) & 3][l15][quad * 8]);
        const bf16x8 A2b = *reinterpret_cast<const bf16x8*>(&h2_s[(SEQ - 2) & 3][l15][32 + quad * 8]);
        floatx4 z[4];
        #pragma unroll
        for (int g = 0; g < 4; ++g) {
            z[g] = floatx4{bcs[g], bcs[g], bcs[g], bcs[g]};
            z[g] = MFMA(A1a, Wf[0][g], z[g]);
            z[g] = MFMA(A1b, Wf[1][g], z[g]);
            z[g] = MFMA(A2a, Wf[2][g], z[g]);
            z[g] = MFMA(A2b, Wf[3][g], z[g]);
        }
        float* h2f = &x_s[0][0];               // repurpose x stage as [16][64] f32
        #pragma unroll
        for (int r = 0; r < 4; ++r) {
            float cc = cst[r];
            h2f[(quad * 4 + r) * HID + hcol] = lstm_gate(z[0][r], z[1][r], z[2][r], z[3][r], cc);
        }
    }
    __syncthreads();

    // ---- epilogue: relu(h2 @ Wd1^T + bd1) @ Wd2^T + bd2 ----
    const float* h2f = &x_s[0][0];
    for (int idx = tid; idx < 16 * 32; idx += 512) {
        const int b = idx >> 5, o = idx & 31;
        float acc = bd1[o];
        #pragma unroll 8
        for (int k = 0; k < HID; ++k) acc += h2f[b * HID + k] * Wd1[o * HID + k];
        y1_s[b][o] = fmaxf(acc, 0.0f);
    }
    __syncthreads();
    for (int idx = tid; idx < 16 * 24; idx += 512) {
        const int b = idx / 24, o = idx - b * 24;
        float acc = bd2[o];
        #pragma unroll 8
        for (int k = 0; k < 32; ++k) acc += y1_s[b][k] * Wd2[o * 32 + k];
        out[(size_t)(b0 + b) * 24 + o] = acc;
    }
}

extern "C" void kernel_launch(void* const* d_in, const int* in_sizes, int n_in,
                              void* d_out, int out_size, void* d_ws, size_t ws_size,
                              hipStream_t stream) {
    const float* x    = (const float*)d_in[0];
    const float* Wih1 = (const float*)d_in[1];
    const float* Whh1 = (const float*)d_in[2];
    const float* bih1 = (const float*)d_in[3];
    const float* bhh1 = (const float*)d_in[4];
    const float* Wih2 = (const float*)d_in[5];
    const float* Whh2 = (const float*)d_in[6];
    const float* bih2 = (const float*)d_in[7];
    const float* bhh2 = (const float*)d_in[8];
    const float* Wd1  = (const float*)d_in[9];
    const float* bd1  = (const float*)d_in[10];
    const float* Wd2  = (const float*)d_in[11];
    const float* bd2  = (const float*)d_in[12];
    float* out = (float*)d_out;

    lstm_fused<<<256, 512, 0, stream>>>(x, Wih1, Whh1, bih1, bhh1,
                                        Wih2, Whh2, bih2, bhh2,
                                        Wd1, bd1, Wd2, bd2, out);
}

// Round 5
// 476.081 us; speedup vs baseline: 1.1257x; 1.1257x over previous
//
#include <hip/hip_runtime.h>

// Fused 2-layer LSTM (B=4096, S=512, H=64) + dense(64->32 relu)->dense(32->24).
// R5: ANTI-PHASE two-interval step. 512-thr WG (8 waves) per 16-row tile,
// grid=256=1 WG/CU. Waves 0-3: layer-1; waves 4-7: layer-2.
// Each step has 2 barriers; between them L1 and L2 waves are in OPPOSITE
// phases so each SIMD always has one trans-heavy wave issuing while the other
// wave's ds_read/MFMA latency hides under it:
//   interval 1: L1 = read h1[t-1] + 8 MFMA (hold z1)   | L2 = gates(z2 held) -> h2[t-2]
//   interval 2: L1 = gates(z1) -> h1[t]                | L2 = read + 16 MFMA (hold z2[t-1])
// z2[t-1] = b2 + Wih2@h1[t-1] + Whh2@h2[t-2] is consumed one step later, so
// L2's MFMA latency crosses a barrier for free. Parity-2 LDS rings for h1/h2
// (every producer->consumer pair separated by >=1 barrier; verified per slot).

typedef __attribute__((ext_vector_type(8))) short bf16x8;
typedef __attribute__((ext_vector_type(4))) float floatx4;

#define SEQ 512
#define HID 64
#define LOG2E 1.4426950408889634f

__device__ inline floatx4 MFMA(bf16x8 a, bf16x8 b, floatx4 c) {
    return __builtin_amdgcn_mfma_f32_16x16x32_bf16(a, b, c, 0, 0, 0);
}
__device__ inline short f2bf(float f) {
    __bf16 b = (__bf16)f;
    return __builtin_bit_cast(short, b);
}
__device__ inline float exp2_fast(float x) {
#if __has_builtin(__builtin_amdgcn_exp2f)
    return __builtin_amdgcn_exp2f(x);
#else
    return __expf(x * 0.6931471805599453f);
#endif
}
__device__ inline float rcp_fast(float x) { return __builtin_amdgcn_rcpf(x); }

// z* pre-scaled: zi=-i*log2e, zf=-f*log2e, zg=-2g*log2e, zo=-o*log2e.
// 5 exp + 2 rcp per element (i/f/g denominators merged; o shares rcp with tanh(c)).
__device__ inline float lstm_gate(float zi, float zf, float zg, float zo, float& c) {
    float ei = exp2_fast(zi);
    float ef = exp2_fast(zf);
    float eg = exp2_fast(zg);
    float eo = exp2_fast(zo);
    float P  = (1.0f + ei) * (1.0f + eg);
    float F  = 1.0f + ef;
    float num = c * P + (1.0f - eg) * F;
    c = num * rcp_fast(P * F);
    float ec = exp2_fast(fminf(c * (-2.0f * LOG2E), 40.0f));
    return (1.0f - ec) * rcp_fast((1.0f + eo) * (1.0f + ec));
}

__global__ __launch_bounds__(512, 2) void lstm_fused(
    const float* __restrict__ x,
    const float* __restrict__ Wih1, const float* __restrict__ Whh1,
    const float* __restrict__ bih1, const float* __restrict__ bhh1,
    const float* __restrict__ Wih2, const float* __restrict__ Whh2,
    const float* __restrict__ bih2, const float* __restrict__ bhh2,
    const float* __restrict__ Wd1,  const float* __restrict__ bd1,
    const float* __restrict__ Wd2,  const float* __restrict__ bd2,
    float* __restrict__ out)
{
    const int tid  = threadIdx.x;
    const int wave = tid >> 6;
    const int ct   = wave & 3;       // column-tile (h-cols [16ct,16ct+16))
    const int is2  = wave >> 2;      // 0: layer-1 wave, 1: layer-2 wave
    const int lane = tid & 63;
    const int l15  = lane & 15;
    const int quad = lane >> 4;
    const int b0   = blockIdx.x * 16;

    __shared__ __align__(16) float x_s[16][516];     // 33 KB
    __shared__ __align__(16) short h1_s[2][16][72];  // parity ring
    __shared__ __align__(16) short h2_s[2][16][72];
    __shared__ float y1_s[16][32];

    // ---- stage x tile (16 rows x 512 f32) ----
    {
        const int row = tid >> 5;
        const int c0  = (tid & 31) * 16;
        const float4* src = reinterpret_cast<const float4*>(x + (size_t)(b0 + row) * SEQ + c0);
        float4* dst = reinterpret_cast<float4*>(&x_s[row][c0]);
        #pragma unroll
        for (int j = 0; j < 4; ++j) dst[j] = src[j];
    }
    for (int i = tid; i < 2 * 16 * 72; i += 512) {   // zero both parities of both rings
        (&h1_s[0][0][0])[i] = 0;
        (&h2_s[0][0][0])[i] = 0;
    }

    // ---- per-wave weight B-fragments (pre-scaled by -log2e; gate g: -2log2e) ----
    // L1 waves: Wf[0..1] = Whh1 K-halves. L2 waves: Wf[0..1]=Wih2, Wf[2..3]=Whh2.
    bf16x8 Wf[4][4];
    float wxc[4], bcs[4];
    #pragma unroll
    for (int g = 0; g < 4; ++g) {
        const float sc = (g == 2) ? (-2.0f * LOG2E) : (-LOG2E);
        const int col = g * 64 + ct * 16 + l15;
        if (!is2) {
            wxc[g] = Wih1[col] * sc;
            bcs[g] = (bih1[col] + bhh1[col]) * sc;
        } else {
            wxc[g] = 0.0f;
            bcs[g] = (bih2[col] + bhh2[col]) * sc;
        }
        #pragma unroll
        for (int kt = 0; kt < 2; ++kt) {
            const int koff = kt * 32 + quad * 8;
            union { short s[8]; bf16x8 v; } u0, u1;
            #pragma unroll
            for (int j = 0; j < 8; ++j) {
                if (!is2) {
                    u0.s[j] = f2bf(Whh1[col * HID + koff + j] * sc);
                    u1.s[j] = 0;
                } else {
                    u0.s[j] = f2bf(Wih2[col * HID + koff + j] * sc);
                    u1.s[j] = f2bf(Whh2[col * HID + koff + j] * sc);
                }
            }
            Wf[kt][g] = u0.v;
            Wf[2 + kt][g] = u1.v;
        }
    }

    const int hcol = ct * 16 + l15;
    float cst[4] = {0, 0, 0, 0};
    floatx4 zh[4];                    // L2: held z2[t-1]; L1: held z1[t] (per-iter)
    #pragma unroll
    for (int g = 0; g < 4; ++g) zh[g] = floatx4{bcs[g], bcs[g], bcs[g], bcs[g]};

    __syncthreads();   // x staged, rings zeroed

    for (int t = 0; t < SEQ; ++t) {
        floatx4 z1[4];
        // ======== interval 1 ========
        if (!is2) {
            // L1: read h1[t-1] (slot (t+1)&1), z-init, 8 MFMA -> hold z1
            const bf16x8 A1a = *reinterpret_cast<const bf16x8*>(&h1_s[(t + 1) & 1][l15][quad * 8]);
            const bf16x8 A1b = *reinterpret_cast<const bf16x8*>(&h1_s[(t + 1) & 1][l15][32 + quad * 8]);
            #pragma unroll
            for (int g = 0; g < 4; ++g)
                #pragma unroll
                for (int r = 0; r < 4; ++r)
                    z1[g][r] = x_s[quad * 4 + r][t] * wxc[g] + bcs[g];
            #pragma unroll
            for (int g = 0; g < 4; ++g) {
                z1[g] = MFMA(A1a, Wf[0][g], z1[g]);
                z1[g] = MFMA(A1b, Wf[1][g], z1[g]);
            }
        } else if (t >= 1) {
            // L2: gates on held z2[t-2] -> h2[t-2] (slot t&1); masked at t==1
            const float m2 = (t >= 2) ? 1.0f : 0.0f;
            #pragma unroll
            for (int r = 0; r < 4; ++r) {
                float cc = cst[r];
                float hv = lstm_gate(zh[0][r], zh[1][r], zh[2][r], zh[3][r], cc) * m2;
                cst[r] = cc * m2;
                h2_s[t & 1][quad * 4 + r][hcol] = f2bf(hv);
            }
        }
        __syncthreads();
        // ======== interval 2 ========
        if (!is2) {
            // L1: gates(z1) -> h1[t] (slot t&1)
            #pragma unroll
            for (int r = 0; r < 4; ++r) {
                float hv = lstm_gate(z1[0][r], z1[1][r], z1[2][r], z1[3][r], cst[r]);
                h1_s[t & 1][quad * 4 + r][hcol] = f2bf(hv);
            }
        } else {
            // L2: hold z2[t-1] = b2 + Wih2@h1[t-1] (slot (t+1)&1) + Whh2@h2[t-2] (slot t&1)
            const bf16x8 A1a = *reinterpret_cast<const bf16x8*>(&h1_s[(t + 1) & 1][l15][quad * 8]);
            const bf16x8 A1b = *reinterpret_cast<const bf16x8*>(&h1_s[(t + 1) & 1][l15][32 + quad * 8]);
            const bf16x8 A2a = *reinterpret_cast<const bf16x8*>(&h2_s[t & 1][l15][quad * 8]);
            const bf16x8 A2b = *reinterpret_cast<const bf16x8*>(&h2_s[t & 1][l15][32 + quad * 8]);
            #pragma unroll
            for (int g = 0; g < 4; ++g) {
                floatx4 z = floatx4{bcs[g], bcs[g], bcs[g], bcs[g]};
                z = MFMA(A1a, Wf[0][g], z);
                z = MFMA(A1b, Wf[1][g], z);
                z = MFMA(A2a, Wf[2][g], z);
                z = MFMA(A2b, Wf[3][g], z);
                zh[g] = z;
            }
        }
        __syncthreads();
    }

    // ---- drain: gates(z2[S-2]) -> h2[S-2]; then z2[S-1] -> h_last ----
    if (is2) {
        #pragma unroll
        for (int r = 0; r < 4; ++r) {
            float hv = lstm_gate(zh[0][r], zh[1][r], zh[2][r], zh[3][r], cst[r]);
            h2_s[SEQ & 1][quad * 4 + r][hcol] = f2bf(hv);   // h2[S-2] -> slot (S-2)&1
        }
    }
    __syncthreads();
    if (is2) {
        const bf16x8 A1a = *reinterpret_cast<const bf16x8*>(&h1_s[(SEQ + 1) & 1][l15][quad * 8]);      // h1[S-1]
        const bf16x8 A1b = *reinterpret_cast<const bf16x8*>(&h1_s[(SEQ + 1) & 1][l15][32 + quad * 8]);
        const bf16x8 A2a = *reinterpret_cast<const bf16x8*>(&h2_s[SEQ & 1][l15][quad * 8]);            // h2[S-2]
        const bf16x8 A2b = *reinterpret_cast<const bf16x8*>(&h2_s[SEQ & 1][l15][32 + quad * 8]);
        floatx4 z[4];
        #pragma unroll
        for (int g = 0; g < 4; ++g) {
            z[g] = floatx4{bcs[g], bcs[g], bcs[g], bcs[g]};
            z[g] = MFMA(A1a, Wf[0][g], z[g]);
            z[g] = MFMA(A1b, Wf[1][g], z[g]);
            z[g] = MFMA(A2a, Wf[2][g], z[g]);
            z[g] = MFMA(A2b, Wf[3][g], z[g]);
        }
        float* h2f = &x_s[0][0];               // repurpose x stage as [16][64] f32
        #pragma unroll
        for (int r = 0; r < 4; ++r) {
            float cc = cst[r];
            h2f[(quad * 4 + r) * HID + hcol] = lstm_gate(z[0][r], z[1][r], z[2][r], z[3][r], cc);
        }
    }
    __syncthreads();

    // ---- epilogue: relu(h2 @ Wd1^T + bd1) @ Wd2^T + bd2 ----
    const float* h2f = &x_s[0][0];
    for (int idx = tid; idx < 16 * 32; idx += 512) {
        const int b = idx >> 5, o = idx & 31;
        float acc = bd1[o];
        #pragma unroll 8
        for (int k = 0; k < HID; ++k) acc += h2f[b * HID + k] * Wd1[o * HID + k];
        y1_s[b][o] = fmaxf(acc, 0.0f);
    }
    __syncthreads();
    for (int idx = tid; idx < 16 * 24; idx += 512) {
        const int b = idx / 24, o = idx - b * 24;
        float acc = bd2[o];
        #pragma unroll 8
        for (int k = 0; k < 32; ++k) acc += y1_s[b][k] * Wd2[o * 32 + k];
        out[(size_t)(b0 + b) * 24 + o] = acc;
    }
}

extern "C" void kernel_launch(void* const* d_in, const int* in_sizes, int n_in,
                              void* d_out, int out_size, void* d_ws, size_t ws_size,
                              hipStream_t stream) {
    const float* x    = (const float*)d_in[0];
    const float* Wih1 = (const float*)d_in[1];
    const float* Whh1 = (const float*)d_in[2];
    const float* bih1 = (const float*)d_in[3];
    const float* bhh1 = (const float*)d_in[4];
    const float* Wih2 = (const float*)d_in[5];
    const float* Whh2 = (const float*)d_in[6];
    const float* bih2 = (const float*)d_in[7];
    const float* bhh2 = (const float*)d_in[8];
    const float* Wd1  = (const float*)d_in[9];
    const float* bd1  = (const float*)d_in[10];
    const float* Wd2  = (const float*)d_in[11];
    const float* bd2  = (const float*)d_in[12];
    float* out = (float*)d_out;

    lstm_fused<<<256, 512, 0, stream>>>(x, Wih1, Whh1, bih1, bhh1,
                                        Wih2, Whh2, bih2, bhh2,
                                        Wd1, bd1, Wd2, bd2, out);
}